// Round 4
// baseline (280.704 us; speedup 1.0000x reference)
//
#include <hip/hip_runtime.h>

// Problem constants (B=8, N=8192, C=256, K=8, nblocks=8, blk=32)
#define NPTS 8192
#define CH   256
#define KNB  8
#define NROWS 65536        // B*N
#define ROWS_PER_BLK 32
#define PHASE_ROWS 16
#define FT_STRIDE 36       // fT row stride: 16B-aligned, <=2-way bank alias (free)

#define NBLK_CONV 8192     // NROWS*CH/(256*8)
#define NBLK_S1   (NROWS / ROWS_PER_BLK)   // 2048
#define NBLK_S2   (NROWS / 16)             // 4096

typedef unsigned short ushort_t;
typedef float  f32x4  __attribute__((ext_vector_type(4)));   // native vec: nontemporal + v_pk_fma_f32

// Raw barrier: LDS ordering only (lgkmcnt drains ds ops); global loads stay
// in flight across it (hipcc's __syncthreads would emit vmcnt(0) and kill the
// gather pipeline). All cross-wave traffic here is LDS, so this is sufficient.
#define BARRIER_LDS() do { \
    asm volatile("s_waitcnt lgkmcnt(0)" ::: "memory"); \
    __builtin_amdgcn_s_barrier(); \
} while (0)

// XCD-aware swizzle: 8 batches == 8 XCDs. Block h -> XCD h%8 (round-robin),
// remap so XCD i exclusively owns batch i: gather working set (4 MB bf16
// slice) fits the XCD-private 4 MiB L2; conv->stage1->stage2 chains in-L2.
__device__ __forceinline__ int xcd_swz(int h, int cpx) {
    return (h & 7) * cpx + (h >> 3);     // bijective: grid % 8 == 0 everywhere
}

__device__ __forceinline__ ushort_t f32_to_bf16(float f) {
    unsigned int b = __float_as_uint(f);
    b += 0x7FFFu + ((b >> 16) & 1u);
    return (ushort_t)(b >> 16);
}
__device__ __forceinline__ float bf16_to_f32(ushort_t u) {
    return __uint_as_float(((unsigned int)u) << 16);
}
__device__ __forceinline__ unsigned int pack_bf16(float lo, float hi) {
    return (unsigned int)f32_to_bf16(lo) | ((unsigned int)f32_to_bf16(hi) << 16);
}
__device__ __forceinline__ f32x4 bf4(ushort4 u) {
    f32x4 r;
    r.x = bf16_to_f32(u.x); r.y = bf16_to_f32(u.y);
    r.z = bf16_to_f32(u.z); r.w = bf16_to_f32(u.w);
    return r;
}

// ---------------------------------------------------------------------------
// Prepass: x fp32 -> bf16, XCD-pinned so batch i's xb slice lands in XCD i's L2.
// ---------------------------------------------------------------------------
__global__ __launch_bounds__(256) void pm_conv(
    const f32x4* __restrict__ x, uint4* __restrict__ xb)
{
    const int l = xcd_swz(blockIdx.x, NBLK_CONV / 8);
    const size_t i = (size_t)l * 256 + threadIdx.x;
    const f32x4 a = __builtin_nontemporal_load(&x[2 * i]);
    const f32x4 c = __builtin_nontemporal_load(&x[2 * i + 1]);
    uint4 o;
    o.x = pack_bf16(a.x, a.y);
    o.y = pack_bf16(a.z, a.w);
    o.z = pack_bf16(c.x, c.y);
    o.w = pack_bf16(c.z, c.w);
    xb[i] = o;
}

// ---------------------------------------------------------------------------
// Stage 1: s1 = rectify(x_bf16); t = monarch(s1) -> bf16.
// 16-row phases: blend 16 rows barrier-free (2-deep gather pipeline), then
// stage A (all 16 rows) and stage B (all 16 rows). 2 barriers/phase = 4 per
// block vs previous 16. FMA loops in ext_vector f32x4 -> v_pk_fma_f32.
// Weights loaded once per phase into registers with asm keep-alive (prevents
// LLVM rematerializing the loads inside the row loops; VGPR=60 showed they
// were never register-resident before).
// ---------------------------------------------------------------------------
__global__ __launch_bounds__(256, 4) void pm_stage1(
    const ushort_t* __restrict__ xb, const float* __restrict__ dist,
    const int* __restrict__ idx, const float* __restrict__ w1,
    const float* __restrict__ w2, const float* __restrict__ bias,
    ushort_t* __restrict__ t)
{
    const int c = threadIdx.x;

    __shared__ float s1[PHASE_ROWS][CH];              // 16 KiB
    __shared__ float fT[PHASE_ROWS][8 * FT_STRIDE];   // 18 KiB

    const float bb = bias[c];
    const int l2   = c & 7;
    const int kb   = c >> 5;
    const int ftw  = l2 * FT_STRIDE + (c >> 3);   // stage A output slot

    const int rr   = __builtin_amdgcn_readfirstlane(threadIdx.x >> 6);
    const int lane = threadIdx.x & 63;

    const int lb       = xcd_swz(blockIdx.x, NBLK_S1 / 8);
    const int row_base = lb * ROWS_PER_BLK;
    const int b = row_base >> 13;                 // == blockIdx.x & 7 == XCD id
    const char* xbase  = (const char*)(xb + (size_t)b * NPTS * CH);
    const int laneoff  = lane * 8;                // 8 B per ushort4

#define LOAD_META(dd, nn, row) do {                                        \
    const float4 m0_ = *(const float4*)(dist + (size_t)(row) * KNB);       \
    const float4 m1_ = *(const float4*)(dist + (size_t)(row) * KNB + 4);   \
    const int4   j0_ = *(const int4*)(idx + (size_t)(row) * KNB);          \
    const int4   j1_ = *(const int4*)(idx + (size_t)(row) * KNB + 4);      \
    dd[0]=m0_.x; dd[1]=m0_.y; dd[2]=m0_.z; dd[3]=m0_.w;                    \
    dd[4]=m1_.x; dd[5]=m1_.y; dd[6]=m1_.z; dd[7]=m1_.w;                    \
    nn[0]=__builtin_amdgcn_readfirstlane(j0_.x);                           \
    nn[1]=__builtin_amdgcn_readfirstlane(j0_.y);                           \
    nn[2]=__builtin_amdgcn_readfirstlane(j0_.z);                           \
    nn[3]=__builtin_amdgcn_readfirstlane(j0_.w);                           \
    nn[4]=__builtin_amdgcn_readfirstlane(j1_.x);                           \
    nn[5]=__builtin_amdgcn_readfirstlane(j1_.y);                           \
    nn[6]=__builtin_amdgcn_readfirstlane(j1_.z);                           \
    nn[7]=__builtin_amdgcn_readfirstlane(j1_.w);                           \
} while (0)

#define ISSUE_G(cc, gg, nn, row) do {                                      \
    const int rloc_ = (row) & (NPTS - 1);                                  \
    cc = *(const ushort4*)(xbase + ((size_t)rloc_ << 9) + laneoff);        \
    _Pragma("unroll")                                                      \
    for (int k_ = 0; k_ < KNB; ++k_)                                       \
        gg[k_] = *(const ushort4*)(xbase + ((size_t)(unsigned)nn[k_] << 9) + laneoff); \
} while (0)

#define BLEND(cc, gg, dd, srow) do {                                       \
    float mn_ = dd[0];                                                     \
    _Pragma("unroll")                                                      \
    for (int k_ = 1; k_ < KNB; ++k_) mn_ = fminf(mn_, dd[k_]);             \
    float e_[KNB]; float sum_ = 0.f;                                       \
    _Pragma("unroll")                                                      \
    for (int k_ = 0; k_ < KNB; ++k_) { e_[k_] = __expf(mn_ - dd[k_]); sum_ += e_[k_]; } \
    const float inv_ = 0.05f / sum_;                                       \
    f32x4 acc_ = 0.95f * bf4(cc);                                          \
    _Pragma("unroll")                                                      \
    for (int k_ = 0; k_ < KNB; ++k_) acc_ += (e_[k_] * inv_) * bf4(gg[k_]); \
    *(f32x4*)(&s1[srow][lane * 4]) = acc_;                                 \
} while (0)

    // meta + gather double buffers (A = even sub, B = odd sub)
    float dA[KNB], dB[KNB];
    int   nA[KNB], nB[KNB];
    ushort4 cA, gA[KNB], cB, gB[KNB];

    // prologue: phase-0 sub0/sub1
    LOAD_META(dA, nA, row_base + rr);
    LOAD_META(dB, nB, row_base + 4 + rr);
    ISSUE_G(cA, gA, nA, row_base + rr);
    ISSUE_G(cB, gB, nB, row_base + 4 + rr);

#pragma unroll
    for (int ph = 0; ph < 2; ++ph) {
        const int prow = row_base + ph * PHASE_ROWS + rr;

        // ---- blend 16 rows (no barriers inside; 2-deep gather pipeline) ----
        BLEND(cA, gA, dA, 0 * 4 + rr);
        LOAD_META(dA, nA, prow + 8);  ISSUE_G(cA, gA, nA, prow + 8);    // sub2
        BLEND(cB, gB, dB, 1 * 4 + rr);
        LOAD_META(dB, nB, prow + 12); ISSUE_G(cB, gB, nB, prow + 12);   // sub3
        BLEND(cA, gA, dA, 2 * 4 + rr);
        BLEND(cB, gB, dB, 3 * 4 + rr);

        BARRIER_LDS();   // s1 ready; separates prev stage-B fT reads from next fT writes

        // ---- stage A: f[c] = sum_p w1[kb,q,p]*s1[kb*32+p] -> fT transposed ----
        f32x4 w1r[8];
        {
            const f32x4* w1p = (const f32x4*)(w1 + c * 32);
#pragma unroll
            for (int i = 0; i < 8; ++i) { w1r[i] = w1p[i]; asm volatile("" : "+v"(w1r[i])); }
        }
#pragma unroll
        for (int r2 = 0; r2 < PHASE_ROWS; ++r2) {
            const f32x4* sb = (const f32x4*)(&s1[r2][kb * 32]); // 2 addrs/wave: free
            f32x4 a4 = {0.f, 0.f, 0.f, 0.f};
#pragma unroll
            for (int p4 = 0; p4 < 8; ++p4) a4 += w1r[p4] * sb[p4];
            fT[r2][ftw] = (a4.x + a4.y) + (a4.z + a4.w);    // <=2-way bank alias
        }

        // cross-phase prefetch: next phase's sub0/sub1 gathers fly across
        // the barrier and stage B
        if (ph == 0) {
            LOAD_META(dA, nA, row_base + PHASE_ROWS + rr);
            ISSUE_G(cA, gA, nA, row_base + PHASE_ROWS + rr);
            LOAD_META(dB, nB, row_base + PHASE_ROWS + 4 + rr);
            ISSUE_G(cB, gB, nB, row_base + PHASE_ROWS + 4 + rr);
        }

        BARRIER_LDS();   // fT ready

        // ---- stage B: t[c] = bias + sum_r w2[l2,s,r]*f[r*8+l2] ----
        f32x4 w2r[8];
        {
            const f32x4* w2p = (const f32x4*)(w2 + ((c & 7) * 32 + (c >> 3)) * 32);
#pragma unroll
            for (int i = 0; i < 8; ++i) { w2r[i] = w2p[i]; asm volatile("" : "+v"(w2r[i])); }
        }
#pragma unroll
        for (int r2 = 0; r2 < PHASE_ROWS; ++r2) {
            const f32x4* fp = (const f32x4*)(&fT[r2][l2 * FT_STRIDE]); // 8 addrs: free
            f32x4 a4 = {0.f, 0.f, 0.f, 0.f};
#pragma unroll
            for (int r4 = 0; r4 < 8; ++r4) a4 += w2r[r4] * fp[r4];
            const float a = bb + ((a4.x + a4.y) + (a4.z + a4.w));
            __builtin_nontemporal_store(
                f32_to_bf16(a),
                &t[(size_t)(row_base + ph * PHASE_ROWS + r2) * CH + c]);
        }
        // no barrier: next phase's post-blend barrier fences fT WAR
    }
#undef LOAD_META
#undef ISSUE_G
#undef BLEND
}

// ---------------------------------------------------------------------------
// Stage 2: out = 0.95*t + 0.05*sum_k w_k*t[b,idx_k] + rf  (t bf16)
// One wave per 4 rows; all 36 gathers + 4 rf loads issued before consumption.
// Gather addresses SGPR-based (readfirstlane'd idx); blend math in f32x4
// (v_pk_fma_f32). rf/out streaming nontemporal so t stays L2-resident.
// ---------------------------------------------------------------------------
__global__ __launch_bounds__(256, 4) void pm_stage2(
    const ushort_t* __restrict__ t, const float* __restrict__ dist,
    const int* __restrict__ idx, const float* __restrict__ rf,
    float* __restrict__ out)
{
    const int w     = __builtin_amdgcn_readfirstlane(threadIdx.x >> 6);
    const int lane  = threadIdx.x & 63;
    const int lb    = xcd_swz(blockIdx.x, NBLK_S2 / 8);
    const int wrow0 = lb * 16 + w * 4;
    const int b     = wrow0 >> 13;               // == blockIdx.x & 7 == XCD id
    const char* tbase = (const char*)(t + (size_t)b * NPTS * CH);
    const int laneoff = lane * 8;

    int   nbs[4][KNB];
    float d [4][KNB];
#pragma unroll
    for (int r = 0; r < 4; ++r) {
        const int row = wrow0 + r;
        const float4 d0 = *(const float4*)(dist + (size_t)row * KNB);
        const float4 d1 = *(const float4*)(dist + (size_t)row * KNB + 4);
        const int4   i0 = *(const int4*)(idx + (size_t)row * KNB);
        const int4   i1 = *(const int4*)(idx + (size_t)row * KNB + 4);
        d[r][0]=d0.x; d[r][1]=d0.y; d[r][2]=d0.z; d[r][3]=d0.w;
        d[r][4]=d1.x; d[r][5]=d1.y; d[r][6]=d1.z; d[r][7]=d1.w;
        nbs[r][0]=__builtin_amdgcn_readfirstlane(i0.x);
        nbs[r][1]=__builtin_amdgcn_readfirstlane(i0.y);
        nbs[r][2]=__builtin_amdgcn_readfirstlane(i0.z);
        nbs[r][3]=__builtin_amdgcn_readfirstlane(i0.w);
        nbs[r][4]=__builtin_amdgcn_readfirstlane(i1.x);
        nbs[r][5]=__builtin_amdgcn_readfirstlane(i1.y);
        nbs[r][6]=__builtin_amdgcn_readfirstlane(i1.z);
        nbs[r][7]=__builtin_amdgcn_readfirstlane(i1.w);
    }

    // issue everything
    ushort4 c0[4], g[4][KNB];
    f32x4   rv[4];
#pragma unroll
    for (int r = 0; r < 4; ++r) {
        const int rloc = (wrow0 + r) & (NPTS - 1);
        c0[r] = *(const ushort4*)(tbase + ((size_t)rloc << 9) + laneoff);
        rv[r] = __builtin_nontemporal_load(
                    &((const f32x4*)rf)[(size_t)(wrow0 + r) * 64 + lane]);
#pragma unroll
        for (int k = 0; k < KNB; ++k)
            g[r][k] = *(const ushort4*)(tbase + ((size_t)(unsigned)nbs[r][k] << 9) + laneoff);
    }

#pragma unroll
    for (int r = 0; r < 4; ++r) {
        float mn = d[r][0];
#pragma unroll
        for (int k = 1; k < KNB; ++k) mn = fminf(mn, d[r][k]);
        float e[KNB]; float sum = 0.f;
#pragma unroll
        for (int k = 0; k < KNB; ++k) { e[k] = __expf(mn - d[r][k]); sum += e[k]; }
        const float inv = 0.05f / sum;

        f32x4 acc = 0.95f * bf4(c0[r]) + rv[r];
#pragma unroll
        for (int k = 0; k < KNB; ++k)
            acc += (e[k] * inv) * bf4(g[r][k]);
        __builtin_nontemporal_store(
            acc, &((f32x4*)out)[(size_t)(wrow0 + r) * 64 + lane]);
    }
}

extern "C" void kernel_launch(void* const* d_in, const int* in_sizes, int n_in,
                              void* d_out, int out_size, void* d_ws, size_t ws_size,
                              hipStream_t stream) {
    const float* x    = (const float*)d_in[0];
    const float* dist = (const float*)d_in[1];
    const int*   idx  = (const int*)d_in[2];
    const float* rf   = (const float*)d_in[3];
    const float* w1   = (const float*)d_in[4];
    const float* w2   = (const float*)d_in[5];
    const float* bias = (const float*)d_in[6];
    float* out = (float*)d_out;

    ushort_t* t  = (ushort_t*)d_ws;                                   // 32 MiB bf16 t
    ushort_t* xb = (ushort_t*)((char*)d_ws + (size_t)NROWS * CH * 2); // 32 MiB bf16 x

    pm_conv  <<<NBLK_CONV, 256, 0, stream>>>((const f32x4*)x, (uint4*)xb);
    pm_stage1<<<NBLK_S1,   256, 0, stream>>>(xb, dist, idx, w1, w2, bias, t);
    pm_stage2<<<NBLK_S2,   256, 0, stream>>>(t, dist, idx, rf, out);
}

// Round 5
// 274.139 us; speedup vs baseline: 1.0239x; 1.0239x over previous
//
#include <hip/hip_runtime.h>

// Problem constants (B=8, N=8192, C=256, K=8, nblocks=8, blk=32)
#define NPTS 8192
#define CH   256
#define KNB  8
#define NROWS 65536        // B*N
#define ROWS_PER_BLK 32
#define ROWS_PER_IT  4
#define NIT (ROWS_PER_BLK / ROWS_PER_IT)   // 8
#define FT_STRIDE 36       // fT row stride: 16B-aligned, <=2-way bank alias (free)

#define NBLK_CONV 8192     // NROWS*CH/(256*8)
#define NBLK_S1   (NROWS / ROWS_PER_BLK)   // 2048
#define NBLK_S2   (NROWS / 16)             // 4096

typedef unsigned short ushort_t;
typedef float  f32x4  __attribute__((ext_vector_type(4)));   // native vec: nontemporal + v_pk_fma_f32

// Raw barrier: LDS ordering only (lgkmcnt drains ds ops); global loads stay
// in flight across it (hipcc's __syncthreads would emit vmcnt(0) and kill the
// gather pipeline). All cross-wave traffic here is LDS, so this is sufficient.
#define BARRIER_LDS() do { \
    asm volatile("s_waitcnt lgkmcnt(0)" ::: "memory"); \
    __builtin_amdgcn_s_barrier(); \
} while (0)

// XCD-aware swizzle: 8 batches == 8 XCDs. Block h -> XCD h%8 (round-robin),
// remap so XCD i exclusively owns batch i: gather working set (4 MB bf16
// slice) fits the XCD-private 4 MiB L2; conv->stage1->stage2 chains in-L2.
__device__ __forceinline__ int xcd_swz(int h, int cpx) {
    return (h & 7) * cpx + (h >> 3);     // bijective: grid % 8 == 0 everywhere
}

__device__ __forceinline__ ushort_t f32_to_bf16(float f) {
    unsigned int b = __float_as_uint(f);
    b += 0x7FFFu + ((b >> 16) & 1u);
    return (ushort_t)(b >> 16);
}
__device__ __forceinline__ float bf16_to_f32(ushort_t u) {
    return __uint_as_float(((unsigned int)u) << 16);
}
__device__ __forceinline__ unsigned int pack_bf16(float lo, float hi) {
    return (unsigned int)f32_to_bf16(lo) | ((unsigned int)f32_to_bf16(hi) << 16);
}
__device__ __forceinline__ f32x4 bf4(ushort4 u) {
    f32x4 r;
    r.x = bf16_to_f32(u.x); r.y = bf16_to_f32(u.y);
    r.z = bf16_to_f32(u.z); r.w = bf16_to_f32(u.w);
    return r;
}

// ---------------------------------------------------------------------------
// Prepass: x fp32 -> bf16, XCD-pinned so batch i's xb slice lands in XCD i's L2.
// ---------------------------------------------------------------------------
__global__ __launch_bounds__(256) void pm_conv(
    const f32x4* __restrict__ x, uint4* __restrict__ xb)
{
    const int l = xcd_swz(blockIdx.x, NBLK_CONV / 8);
    const size_t i = (size_t)l * 256 + threadIdx.x;
    const f32x4 a = __builtin_nontemporal_load(&x[2 * i]);
    const f32x4 c = __builtin_nontemporal_load(&x[2 * i + 1]);
    uint4 o;
    o.x = pack_bf16(a.x, a.y);
    o.y = pack_bf16(a.z, a.w);
    o.z = pack_bf16(c.x, c.y);
    o.w = pack_bf16(c.z, c.w);
    xb[i] = o;
}

// ---------------------------------------------------------------------------
// Stage 1: s1 = rectify(x_bf16); t = monarch(s1) -> bf16.
// R2 pipeline skeleton (2 LDS-only barriers / 4-row iteration) with:
//  - launch_bounds(256,3): VGPR cap 170 so the 64 weight regs stay RESIDENT
//    (at (256,4)/cap-128 LLVM remats the weight loads inside the K-loops —
//    VGPR_Count=60 proved they never lived in registers).
//  - f32x4 ext-vector FMA (v_pk_fma_f32): halves VALU issue in blend/A/B.
//  - next-row gathers issued immediately after blend: in flight across
//    stage A + barrier + stage B (~full FMA body of latency cover).
// ---------------------------------------------------------------------------
__global__ __launch_bounds__(256, 3) void pm_stage1(
    const ushort_t* __restrict__ xb, const float* __restrict__ dist,
    const int* __restrict__ idx, const float* __restrict__ w1,
    const float* __restrict__ w2, const float* __restrict__ bias,
    ushort_t* __restrict__ t)
{
    const int c = threadIdx.x;

    __shared__ float s1[ROWS_PER_IT][CH];              // 4 KiB
    __shared__ float fT[ROWS_PER_IT][8 * FT_STRIDE];   // 4.5 KiB

    // hoisted weights — pinned once at kernel top (fits under the 170 cap)
    f32x4 w1r[8], w2r[8];
    {
        const f32x4* w1p = (const f32x4*)(w1 + c * 32);
        const f32x4* w2p = (const f32x4*)(w2 + ((c & 7) * 32 + (c >> 3)) * 32);
#pragma unroll
        for (int i = 0; i < 8; ++i) {
            w1r[i] = w1p[i]; w2r[i] = w2p[i];
            asm volatile("" : "+v"(w1r[i]), "+v"(w2r[i]));
        }
    }
    const float bb = bias[c];
    const int l2   = c & 7;
    const int kb   = c >> 5;
    const int ftw  = l2 * FT_STRIDE + (c >> 3);   // stage A output slot

    const int rr   = __builtin_amdgcn_readfirstlane(threadIdx.x >> 6);
    const int lane = threadIdx.x & 63;

    const int lb       = xcd_swz(blockIdx.x, NBLK_S1 / 8);
    const int row_base = lb * ROWS_PER_BLK;
    const int b = row_base >> 13;                 // == blockIdx.x & 7 == XCD id
    const char* xbase  = (const char*)(xb + (size_t)b * NPTS * CH);
    const int laneoff  = lane * 8;                // 8 B per ushort4

    // ---- prologue: row(it=0) metadata + gathers ----
    float dcur[KNB]; int nbs[KNB];
    {
        const int row = row_base + rr;
        const float4 d0 = *(const float4*)(dist + (size_t)row * KNB);
        const float4 d1 = *(const float4*)(dist + (size_t)row * KNB + 4);
        const int4   i0 = *(const int4*)(idx + (size_t)row * KNB);
        const int4   i1 = *(const int4*)(idx + (size_t)row * KNB + 4);
        dcur[0]=d0.x; dcur[1]=d0.y; dcur[2]=d0.z; dcur[3]=d0.w;
        dcur[4]=d1.x; dcur[5]=d1.y; dcur[6]=d1.z; dcur[7]=d1.w;
        nbs[0]=__builtin_amdgcn_readfirstlane(i0.x);
        nbs[1]=__builtin_amdgcn_readfirstlane(i0.y);
        nbs[2]=__builtin_amdgcn_readfirstlane(i0.z);
        nbs[3]=__builtin_amdgcn_readfirstlane(i0.w);
        nbs[4]=__builtin_amdgcn_readfirstlane(i1.x);
        nbs[5]=__builtin_amdgcn_readfirstlane(i1.y);
        nbs[6]=__builtin_amdgcn_readfirstlane(i1.z);
        nbs[7]=__builtin_amdgcn_readfirstlane(i1.w);
    }
    ushort4 c0, g[KNB];
    {
        const int rloc = (row_base + rr) & (NPTS - 1);
        c0 = *(const ushort4*)(xbase + ((size_t)rloc << 9) + laneoff);
#pragma unroll
        for (int k = 0; k < KNB; ++k)
            g[k] = *(const ushort4*)(xbase + ((size_t)(unsigned)nbs[k] << 9) + laneoff);
    }

    for (int it = 0; it < NIT; ++it) {
        const bool more = (it + 1 < NIT);
        const int rown  = row_base + (more ? it + 1 : it) * ROWS_PER_IT + rr;

        // prefetch next row's metadata (covered by the blend below)
        const float4 dn0 = *(const float4*)(dist + (size_t)rown * KNB);
        const float4 dn1 = *(const float4*)(dist + (size_t)rown * KNB + 4);
        const int4   in0 = *(const int4*)(idx + (size_t)rown * KNB);
        const int4   in1 = *(const int4*)(idx + (size_t)rown * KNB + 4);

        // ---- blend (consumes gathers issued last iteration) ----
        float mn = dcur[0];
#pragma unroll
        for (int k = 1; k < KNB; ++k) mn = fminf(mn, dcur[k]);
        float e[KNB]; float sum = 0.f;
#pragma unroll
        for (int k = 0; k < KNB; ++k) { e[k] = __expf(mn - dcur[k]); sum += e[k]; }
        const float inv = 0.05f / sum;

        f32x4 acc = 0.95f * bf4(c0);
#pragma unroll
        for (int k = 0; k < KNB; ++k) acc += (e[k] * inv) * bf4(g[k]);
        *(f32x4*)(&s1[rr][lane * 4]) = acc;

        // ---- handoff + issue next row's gathers NOW: they fly across
        //      stage A + barrier + stage B (the full FMA body) ----
        if (more) {
            dcur[0]=dn0.x; dcur[1]=dn0.y; dcur[2]=dn0.z; dcur[3]=dn0.w;
            dcur[4]=dn1.x; dcur[5]=dn1.y; dcur[6]=dn1.z; dcur[7]=dn1.w;
            nbs[0]=__builtin_amdgcn_readfirstlane(in0.x);
            nbs[1]=__builtin_amdgcn_readfirstlane(in0.y);
            nbs[2]=__builtin_amdgcn_readfirstlane(in0.z);
            nbs[3]=__builtin_amdgcn_readfirstlane(in0.w);
            nbs[4]=__builtin_amdgcn_readfirstlane(in1.x);
            nbs[5]=__builtin_amdgcn_readfirstlane(in1.y);
            nbs[6]=__builtin_amdgcn_readfirstlane(in1.z);
            nbs[7]=__builtin_amdgcn_readfirstlane(in1.w);
            const int rloc = rown & (NPTS - 1);
            c0 = *(const ushort4*)(xbase + ((size_t)rloc << 9) + laneoff);
#pragma unroll
            for (int k = 0; k < KNB; ++k)
                g[k] = *(const ushort4*)(xbase + ((size_t)(unsigned)nbs[k] << 9) + laneoff);
        }

        BARRIER_LDS();   // s1 ready; also fences prev stage-B fT reads vs stage-A writes

        // ---- stage A: f[c] = sum_p w1[kb,q,p]*s1[kb*32+p] -> fT transposed ----
#pragma unroll
        for (int r2 = 0; r2 < ROWS_PER_IT; ++r2) {
            const f32x4* sb = (const f32x4*)(&s1[r2][kb * 32]); // 2 addrs/wave: free
            f32x4 a4 = {0.f, 0.f, 0.f, 0.f};
#pragma unroll
            for (int p4 = 0; p4 < 8; ++p4) a4 += w1r[p4] * sb[p4];
            fT[r2][ftw] = (a4.x + a4.y) + (a4.z + a4.w);    // <=2-way bank alias
        }

        BARRIER_LDS();   // fT ready; also fences stage-A s1 reads vs next blend writes

        // ---- stage B: t[c] = bias + sum_r w2[l2,s,r]*f[r*8+l2] ----
#pragma unroll
        for (int r2 = 0; r2 < ROWS_PER_IT; ++r2) {
            const f32x4* fp = (const f32x4*)(&fT[r2][l2 * FT_STRIDE]); // 8 addrs: free
            f32x4 a4 = {0.f, 0.f, 0.f, 0.f};
#pragma unroll
            for (int r4 = 0; r4 < 8; ++r4) a4 += w2r[r4] * fp[r4];
            const float a = bb + ((a4.x + a4.y) + (a4.z + a4.w));
            __builtin_nontemporal_store(
                f32_to_bf16(a),
                &t[(size_t)(row_base + it * ROWS_PER_IT + r2) * CH + c]);
        }
        // no barrier: next iteration's post-blend barrier fences fT WAR
    }
}

// ---------------------------------------------------------------------------
// Stage 2: out = 0.95*t + 0.05*sum_k w_k*t[b,idx_k] + rf  (t bf16)
// One wave per 4 rows; all 36 gathers + 4 rf loads issued before consumption.
// Gather addresses SGPR-based (readfirstlane'd idx); blend math in f32x4
// (v_pk_fma_f32). rf/out streaming nontemporal so t stays L2-resident.
// ---------------------------------------------------------------------------
__global__ __launch_bounds__(256, 4) void pm_stage2(
    const ushort_t* __restrict__ t, const float* __restrict__ dist,
    const int* __restrict__ idx, const float* __restrict__ rf,
    float* __restrict__ out)
{
    const int w     = __builtin_amdgcn_readfirstlane(threadIdx.x >> 6);
    const int lane  = threadIdx.x & 63;
    const int lb    = xcd_swz(blockIdx.x, NBLK_S2 / 8);
    const int wrow0 = lb * 16 + w * 4;
    const int b     = wrow0 >> 13;               // == blockIdx.x & 7 == XCD id
    const char* tbase = (const char*)(t + (size_t)b * NPTS * CH);
    const int laneoff = lane * 8;

    int   nbs[4][KNB];
    float d [4][KNB];
#pragma unroll
    for (int r = 0; r < 4; ++r) {
        const int row = wrow0 + r;
        const float4 d0 = *(const float4*)(dist + (size_t)row * KNB);
        const float4 d1 = *(const float4*)(dist + (size_t)row * KNB + 4);
        const int4   i0 = *(const int4*)(idx + (size_t)row * KNB);
        const int4   i1 = *(const int4*)(idx + (size_t)row * KNB + 4);
        d[r][0]=d0.x; d[r][1]=d0.y; d[r][2]=d0.z; d[r][3]=d0.w;
        d[r][4]=d1.x; d[r][5]=d1.y; d[r][6]=d1.z; d[r][7]=d1.w;
        nbs[r][0]=__builtin_amdgcn_readfirstlane(i0.x);
        nbs[r][1]=__builtin_amdgcn_readfirstlane(i0.y);
        nbs[r][2]=__builtin_amdgcn_readfirstlane(i0.z);
        nbs[r][3]=__builtin_amdgcn_readfirstlane(i0.w);
        nbs[r][4]=__builtin_amdgcn_readfirstlane(i1.x);
        nbs[r][5]=__builtin_amdgcn_readfirstlane(i1.y);
        nbs[r][6]=__builtin_amdgcn_readfirstlane(i1.z);
        nbs[r][7]=__builtin_amdgcn_readfirstlane(i1.w);
    }

    // issue everything
    ushort4 c0[4], g[4][KNB];
    f32x4   rv[4];
#pragma unroll
    for (int r = 0; r < 4; ++r) {
        const int rloc = (wrow0 + r) & (NPTS - 1);
        c0[r] = *(const ushort4*)(tbase + ((size_t)rloc << 9) + laneoff);
        rv[r] = __builtin_nontemporal_load(
                    &((const f32x4*)rf)[(size_t)(wrow0 + r) * 64 + lane]);
#pragma unroll
        for (int k = 0; k < KNB; ++k)
            g[r][k] = *(const ushort4*)(tbase + ((size_t)(unsigned)nbs[r][k] << 9) + laneoff);
    }

#pragma unroll
    for (int r = 0; r < 4; ++r) {
        float mn = d[r][0];
#pragma unroll
        for (int k = 1; k < KNB; ++k) mn = fminf(mn, d[r][k]);
        float e[KNB]; float sum = 0.f;
#pragma unroll
        for (int k = 0; k < KNB; ++k) { e[k] = __expf(mn - d[r][k]); sum += e[k]; }
        const float inv = 0.05f / sum;

        f32x4 acc = 0.95f * bf4(c0[r]) + rv[r];
#pragma unroll
        for (int k = 0; k < KNB; ++k)
            acc += (e[k] * inv) * bf4(g[r][k]);
        __builtin_nontemporal_store(
            acc, &((f32x4*)out)[(size_t)(wrow0 + r) * 64 + lane]);
    }
}

extern "C" void kernel_launch(void* const* d_in, const int* in_sizes, int n_in,
                              void* d_out, int out_size, void* d_ws, size_t ws_size,
                              hipStream_t stream) {
    const float* x    = (const float*)d_in[0];
    const float* dist = (const float*)d_in[1];
    const int*   idx  = (const int*)d_in[2];
    const float* rf   = (const float*)d_in[3];
    const float* w1   = (const float*)d_in[4];
    const float* w2   = (const float*)d_in[5];
    const float* bias = (const float*)d_in[6];
    float* out = (float*)d_out;

    ushort_t* t  = (ushort_t*)d_ws;                                   // 32 MiB bf16 t
    ushort_t* xb = (ushort_t*)((char*)d_ws + (size_t)NROWS * CH * 2); // 32 MiB bf16 x

    pm_conv  <<<NBLK_CONV, 256, 0, stream>>>((const f32x4*)x, (uint4*)xb);
    pm_stage1<<<NBLK_S1,   256, 0, stream>>>(xb, dist, idx, w1, w2, bias, t);
    pm_stage2<<<NBLK_S2,   256, 0, stream>>>(t, dist, idx, rf, out);
}

// Round 6
// 265.318 us; speedup vs baseline: 1.0580x; 1.0332x over previous
//
#include <hip/hip_runtime.h>

// Problem constants (B=8, N=8192, C=256, K=8, nblocks=8, blk=32)
#define NPTS 8192
#define CH   256
#define KNB  8
#define NROWS 65536        // B*N
#define ROWS_PER_BLK 32
#define ROWS_PER_IT  4
#define NIT (ROWS_PER_BLK / ROWS_PER_IT)   // 8
#define FT_STRIDE 36       // fT row stride: 16B-aligned, <=2-way bank alias (free)

#define NBLK_CONV 8192     // NROWS*CH/(256*8)
#define NBLK_S1   (NROWS / ROWS_PER_BLK)   // 2048
#define NBLK_S2   (NROWS / 16)             // 4096

typedef unsigned short ushort_t;
typedef float  f32x4  __attribute__((ext_vector_type(4)));   // native vec for nontemporal builtins

// Raw barrier: LDS ordering only (lgkmcnt drains ds ops); global loads stay
// in flight across it (hipcc's __syncthreads would emit vmcnt(0) and kill the
// gather pipeline). All cross-wave traffic here is LDS, so this is sufficient.
#define BARRIER_LDS() do { \
    asm volatile("s_waitcnt lgkmcnt(0)" ::: "memory"); \
    __builtin_amdgcn_s_barrier(); \
} while (0)

// XCD-aware swizzle: 8 batches == 8 XCDs. Block h -> XCD h%8 (round-robin),
// remap so XCD i exclusively owns batch i: gather working set (4 MB bf16
// slice) fits the XCD-private 4 MiB L2; conv->stage1->stage2 chains in-L2.
__device__ __forceinline__ int xcd_swz(int h, int cpx) {
    return (h & 7) * cpx + (h >> 3);     // bijective: grid % 8 == 0 everywhere
}

__device__ __forceinline__ ushort_t f32_to_bf16(float f) {
    unsigned int b = __float_as_uint(f);
    b += 0x7FFFu + ((b >> 16) & 1u);
    return (ushort_t)(b >> 16);
}
__device__ __forceinline__ float bf16_to_f32(ushort_t u) {
    return __uint_as_float(((unsigned int)u) << 16);
}
__device__ __forceinline__ unsigned int pack_bf16(float lo, float hi) {
    return (unsigned int)f32_to_bf16(lo) | ((unsigned int)f32_to_bf16(hi) << 16);
}

// ---------------------------------------------------------------------------
// Prepass: x fp32 -> bf16, XCD-pinned so batch i's xb slice lands in XCD i's L2.
// x read is pure streaming -> nontemporal (never re-read).
// ---------------------------------------------------------------------------
__global__ __launch_bounds__(256) void pm_conv(
    const f32x4* __restrict__ x, uint4* __restrict__ xb)
{
    const int l = xcd_swz(blockIdx.x, NBLK_CONV / 8);
    const size_t i = (size_t)l * 256 + threadIdx.x;
    const f32x4 a = __builtin_nontemporal_load(&x[2 * i]);
    const f32x4 c = __builtin_nontemporal_load(&x[2 * i + 1]);
    uint4 o;
    o.x = pack_bf16(a.x, a.y);
    o.y = pack_bf16(a.z, a.w);
    o.z = pack_bf16(c.x, c.y);
    o.w = pack_bf16(c.z, c.w);
    xb[i] = o;
}

// ---------------------------------------------------------------------------
// Stage 1: s1 = rectify(x_bf16); t = monarch(s1) -> bf16.
// Exact R2 structure (best measured: 80.8us): software-pipelined gathers
// (issued after stage A, consumed next blend), SGPR-based gather addresses,
// 2 LDS-only barriers per 4-row iteration, scalar float4 FMA (the FMA stream
// doubles as latency-hiding filler -- packed math made it SLOWER, R4).
// ONE diff vs R2: t stores are NORMAL (not nontemporal) so t write-allocates
// in the XCD L2 -- stage2 gathers t 9x from there. The nt-store protected
// stage1's xb residency but pushed all of stage2's gathers to L3 latency.
// ---------------------------------------------------------------------------
__global__ __launch_bounds__(256, 4) void pm_stage1(
    const ushort_t* __restrict__ xb, const float* __restrict__ dist,
    const int* __restrict__ idx, const float* __restrict__ w1,
    const float* __restrict__ w2, const float* __restrict__ bias,
    ushort_t* __restrict__ t)
{
    const int c = threadIdx.x;

    __shared__ float s1[ROWS_PER_IT][CH];
    __shared__ float fT[ROWS_PER_IT][8 * FT_STRIDE];

    // hoisted weights
    float4 w1r[8], w2r[8];
    {
        const float4* w1p = (const float4*)(w1 + c * 32);
        const float4* w2p = (const float4*)(w2 + ((c & 7) * 32 + (c >> 3)) * 32);
#pragma unroll
        for (int i = 0; i < 8; ++i) { w1r[i] = w1p[i]; w2r[i] = w2p[i]; }
    }
    const float bb = bias[c];
    const int l2   = c & 7;
    const int kb   = c >> 5;
    const int ftw  = l2 * FT_STRIDE + (c >> 3);   // stage A output slot

    const int rr   = __builtin_amdgcn_readfirstlane(threadIdx.x >> 6);
    const int lane = threadIdx.x & 63;

    const int lb       = xcd_swz(blockIdx.x, NBLK_S1 / 8);
    const int row_base = lb * ROWS_PER_BLK;
    const int b = row_base >> 13;                 // == blockIdx.x & 7 == XCD id
    const char* xbase  = (const char*)(xb + (size_t)b * NPTS * CH);
    const int laneoff  = lane * 8;                // 8 B per ushort4

    // ---- prologue: row(it=0) metadata + gathers ----
    float dcur[KNB]; int nbs[KNB];
    {
        const int row = row_base + rr;
        const float4 d0 = *(const float4*)(dist + (size_t)row * KNB);
        const float4 d1 = *(const float4*)(dist + (size_t)row * KNB + 4);
        const int4   i0 = *(const int4*)(idx + (size_t)row * KNB);
        const int4   i1 = *(const int4*)(idx + (size_t)row * KNB + 4);
        dcur[0]=d0.x; dcur[1]=d0.y; dcur[2]=d0.z; dcur[3]=d0.w;
        dcur[4]=d1.x; dcur[5]=d1.y; dcur[6]=d1.z; dcur[7]=d1.w;
        nbs[0]=__builtin_amdgcn_readfirstlane(i0.x);
        nbs[1]=__builtin_amdgcn_readfirstlane(i0.y);
        nbs[2]=__builtin_amdgcn_readfirstlane(i0.z);
        nbs[3]=__builtin_amdgcn_readfirstlane(i0.w);
        nbs[4]=__builtin_amdgcn_readfirstlane(i1.x);
        nbs[5]=__builtin_amdgcn_readfirstlane(i1.y);
        nbs[6]=__builtin_amdgcn_readfirstlane(i1.z);
        nbs[7]=__builtin_amdgcn_readfirstlane(i1.w);
    }
    ushort4 c0, g[KNB];
    {
        const int rloc = (row_base + rr) & (NPTS - 1);
        c0 = *(const ushort4*)(xbase + ((size_t)rloc << 9) + laneoff);
#pragma unroll
        for (int k = 0; k < KNB; ++k)
            g[k] = *(const ushort4*)(xbase + ((size_t)(unsigned)nbs[k] << 9) + laneoff);
    }

    for (int it = 0; it < NIT; ++it) {
        const bool more = (it + 1 < NIT);
        const int rown  = row_base + (more ? it + 1 : it) * ROWS_PER_IT + rr;

        // prefetch next row's metadata (in flight during blend + stage A)
        const float4 dn0 = *(const float4*)(dist + (size_t)rown * KNB);
        const float4 dn1 = *(const float4*)(dist + (size_t)rown * KNB + 4);
        const int4   in0 = *(const int4*)(idx + (size_t)rown * KNB);
        const int4   in1 = *(const int4*)(idx + (size_t)rown * KNB + 4);

        // ---- blend (consumes prefetched gathers) ----
        float mn = dcur[0];
#pragma unroll
        for (int k = 1; k < KNB; ++k) mn = fminf(mn, dcur[k]);
        float e[KNB]; float sum = 0.f;
#pragma unroll
        for (int k = 0; k < KNB; ++k) { e[k] = __expf(mn - dcur[k]); sum += e[k]; }
        const float inv = 0.05f / sum;

        float4 acc;
        acc.x = 0.95f * bf16_to_f32(c0.x);
        acc.y = 0.95f * bf16_to_f32(c0.y);
        acc.z = 0.95f * bf16_to_f32(c0.z);
        acc.w = 0.95f * bf16_to_f32(c0.w);
#pragma unroll
        for (int k = 0; k < KNB; ++k) {
            const float w = e[k] * inv;
            acc.x += w * bf16_to_f32(g[k].x);
            acc.y += w * bf16_to_f32(g[k].y);
            acc.z += w * bf16_to_f32(g[k].z);
            acc.w += w * bf16_to_f32(g[k].w);
        }
        ((float4*)&s1[rr][0])[lane] = acc;

        BARRIER_LDS();   // s1 ready; also fences stageB(it-1) fT reads vs stageA writes

        // ---- stage A: f[c] = sum_p w1[kb,q,p]*s1[kb*32+p] -> fT transposed ----
#pragma unroll
        for (int r2 = 0; r2 < ROWS_PER_IT; ++r2) {
            const float4* sb = (const float4*)(&s1[r2][kb * 32]); // 2 addrs/wave: free
            float a = 0.f;
#pragma unroll
            for (int p4 = 0; p4 < 8; ++p4) {
                const float4 s = sb[p4];
                a += w1r[p4].x * s.x + w1r[p4].y * s.y
                   + w1r[p4].z * s.z + w1r[p4].w * s.w;
            }
            fT[r2][ftw] = a;    // <=2-way bank alias: free
        }

        // ---- handoff + issue next row's gathers (fly across barrier+stageB) ----
        if (more) {
            dcur[0]=dn0.x; dcur[1]=dn0.y; dcur[2]=dn0.z; dcur[3]=dn0.w;
            dcur[4]=dn1.x; dcur[5]=dn1.y; dcur[6]=dn1.z; dcur[7]=dn1.w;
            nbs[0]=__builtin_amdgcn_readfirstlane(in0.x);
            nbs[1]=__builtin_amdgcn_readfirstlane(in0.y);
            nbs[2]=__builtin_amdgcn_readfirstlane(in0.z);
            nbs[3]=__builtin_amdgcn_readfirstlane(in0.w);
            nbs[4]=__builtin_amdgcn_readfirstlane(in1.x);
            nbs[5]=__builtin_amdgcn_readfirstlane(in1.y);
            nbs[6]=__builtin_amdgcn_readfirstlane(in1.z);
            nbs[7]=__builtin_amdgcn_readfirstlane(in1.w);
            const int rloc = rown & (NPTS - 1);
            c0 = *(const ushort4*)(xbase + ((size_t)rloc << 9) + laneoff);
#pragma unroll
            for (int k = 0; k < KNB; ++k)
                g[k] = *(const ushort4*)(xbase + ((size_t)(unsigned)nbs[k] << 9) + laneoff);
        }

        BARRIER_LDS();   // fT ready; also fences stageA s1 reads vs next blend writes

        // ---- stage B: t[c] = bias + sum_r w2[l2,s,r]*f[r*8+l2] ----
#pragma unroll
        for (int r2 = 0; r2 < ROWS_PER_IT; ++r2) {
            const float4* fp = (const float4*)(&fT[r2][l2 * FT_STRIDE]); // 8 addrs: free
            float a = bb;
#pragma unroll
            for (int r4 = 0; r4 < 8; ++r4) {
                const float4 f = fp[r4];
                a += w2r[r4].x * f.x + w2r[r4].y * f.y
                   + w2r[r4].z * f.z + w2r[r4].w * f.w;
            }
            // NORMAL store: t must write-allocate in this XCD's L2 for stage2.
            t[(size_t)(row_base + it * ROWS_PER_IT + r2) * CH + c] = f32_to_bf16(a);
        }
        // no barrier: next iteration's post-blend barrier fences fT WAR
    }
}

// ---------------------------------------------------------------------------
// Stage 2: out = 0.95*t + 0.05*sum_k w_k*t[b,idx_k] + rf  (t bf16)
// One wave per 4 rows; all 36 gathers + 4 rf loads issued before consumption.
// Gather addresses SGPR-based (readfirstlane'd idx). rf/out are streaming ->
// nontemporal, so the 9x-reused t gather slice stays resident in the XCD L2.
// ---------------------------------------------------------------------------
__global__ __launch_bounds__(256, 4) void pm_stage2(
    const ushort_t* __restrict__ t, const float* __restrict__ dist,
    const int* __restrict__ idx, const float* __restrict__ rf,
    float* __restrict__ out)
{
    const int w     = __builtin_amdgcn_readfirstlane(threadIdx.x >> 6);
    const int lane  = threadIdx.x & 63;
    const int lb    = xcd_swz(blockIdx.x, NBLK_S2 / 8);
    const int wrow0 = lb * 16 + w * 4;
    const int b     = wrow0 >> 13;               // == blockIdx.x & 7 == XCD id
    const char* tbase = (const char*)(t + (size_t)b * NPTS * CH);
    const int laneoff = lane * 8;

    int   nbs[4][KNB];
    float d [4][KNB];
#pragma unroll
    for (int r = 0; r < 4; ++r) {
        const int row = wrow0 + r;
        const float4 d0 = *(const float4*)(dist + (size_t)row * KNB);
        const float4 d1 = *(const float4*)(dist + (size_t)row * KNB + 4);
        const int4   i0 = *(const int4*)(idx + (size_t)row * KNB);
        const int4   i1 = *(const int4*)(idx + (size_t)row * KNB + 4);
        d[r][0]=d0.x; d[r][1]=d0.y; d[r][2]=d0.z; d[r][3]=d0.w;
        d[r][4]=d1.x; d[r][5]=d1.y; d[r][6]=d1.z; d[r][7]=d1.w;
        nbs[r][0]=__builtin_amdgcn_readfirstlane(i0.x);
        nbs[r][1]=__builtin_amdgcn_readfirstlane(i0.y);
        nbs[r][2]=__builtin_amdgcn_readfirstlane(i0.z);
        nbs[r][3]=__builtin_amdgcn_readfirstlane(i0.w);
        nbs[r][4]=__builtin_amdgcn_readfirstlane(i1.x);
        nbs[r][5]=__builtin_amdgcn_readfirstlane(i1.y);
        nbs[r][6]=__builtin_amdgcn_readfirstlane(i1.z);
        nbs[r][7]=__builtin_amdgcn_readfirstlane(i1.w);
    }

    // issue everything
    ushort4 c0[4], g[4][KNB];
    f32x4   rv[4];
#pragma unroll
    for (int r = 0; r < 4; ++r) {
        const int rloc = (wrow0 + r) & (NPTS - 1);
        c0[r] = *(const ushort4*)(tbase + ((size_t)rloc << 9) + laneoff);
        rv[r] = __builtin_nontemporal_load(
                    &((const f32x4*)rf)[(size_t)(wrow0 + r) * 64 + lane]);
#pragma unroll
        for (int k = 0; k < KNB; ++k)
            g[r][k] = *(const ushort4*)(tbase + ((size_t)(unsigned)nbs[r][k] << 9) + laneoff);
    }

#pragma unroll
    for (int r = 0; r < 4; ++r) {
        float mn = d[r][0];
#pragma unroll
        for (int k = 1; k < KNB; ++k) mn = fminf(mn, d[r][k]);
        float e[KNB]; float sum = 0.f;
#pragma unroll
        for (int k = 0; k < KNB; ++k) { e[k] = __expf(mn - d[r][k]); sum += e[k]; }
        const float inv = 0.05f / sum;

        f32x4 acc;
        acc.x = 0.95f * bf16_to_f32(c0[r].x) + rv[r].x;
        acc.y = 0.95f * bf16_to_f32(c0[r].y) + rv[r].y;
        acc.z = 0.95f * bf16_to_f32(c0[r].z) + rv[r].z;
        acc.w = 0.95f * bf16_to_f32(c0[r].w) + rv[r].w;
#pragma unroll
        for (int k = 0; k < KNB; ++k) {
            const float wk = e[k] * inv;
            acc.x += wk * bf16_to_f32(g[r][k].x);
            acc.y += wk * bf16_to_f32(g[r][k].y);
            acc.z += wk * bf16_to_f32(g[r][k].z);
            acc.w += wk * bf16_to_f32(g[r][k].w);
        }
        __builtin_nontemporal_store(
            acc, &((f32x4*)out)[(size_t)(wrow0 + r) * 64 + lane]);
    }
}

extern "C" void kernel_launch(void* const* d_in, const int* in_sizes, int n_in,
                              void* d_out, int out_size, void* d_ws, size_t ws_size,
                              hipStream_t stream) {
    const float* x    = (const float*)d_in[0];
    const float* dist = (const float*)d_in[1];
    const int*   idx  = (const int*)d_in[2];
    const float* rf   = (const float*)d_in[3];
    const float* w1   = (const float*)d_in[4];
    const float* w2   = (const float*)d_in[5];
    const float* bias = (const float*)d_in[6];
    float* out = (float*)d_out;

    ushort_t* t  = (ushort_t*)d_ws;                                   // 32 MiB bf16 t
    ushort_t* xb = (ushort_t*)((char*)d_ws + (size_t)NROWS * CH * 2); // 32 MiB bf16 x

    pm_conv  <<<NBLK_CONV, 256, 0, stream>>>((const f32x4*)x, (uint4*)xb);
    pm_stage1<<<NBLK_S1,   256, 0, stream>>>(xb, dist, idx, w1, w2, bias, t);
    pm_stage2<<<NBLK_S2,   256, 0, stream>>>(t, dist, idx, rf, out);
}

// Round 9
// 238.574 us; speedup vs baseline: 1.1766x; 1.1121x over previous
//
#include <hip/hip_runtime.h>

// Problem constants (B=8, N=8192, C=256, K=8, nblocks=8, blk=32)
#define NPTS 8192
#define CH   256
#define KNB  8
#define NROWS 65536        // B*N
#define RPB_S1 32
#define NBLK_CONV 8192     // NROWS*CH/(256*8)
#define NBLK_S1   (NROWS / RPB_S1)   // 2048
#define NBLK_S2   (NROWS / 16)       // 4096

typedef unsigned short ushort_t;
typedef float  f32x4  __attribute__((ext_vector_type(4)));   // native vec: nontemporal + MFMA C/D
typedef short  bf16x8 __attribute__((ext_vector_type(8)));   // MFMA A/B frag (8 bf16)

// Raw barrier: LDS ordering only (lgkmcnt drains ds ops); global loads stay
// in flight across it. All cross-wave traffic in stage1 is LDS, so sufficient.
#define BARRIER_LDS() do { \
    asm volatile("s_waitcnt lgkmcnt(0)" ::: "memory"); \
    __builtin_amdgcn_s_barrier(); \
} while (0)

// XCD-aware swizzle: 8 batches == 8 XCDs; XCD i owns batch i so the 4 MB bf16
// gather slice stays in its private L2.
__device__ __forceinline__ int xcd_swz(int h, int cpx) {
    return (h & 7) * cpx + (h >> 3);     // bijective: grid % 8 == 0 everywhere
}

__device__ __forceinline__ ushort_t f32_to_bf16(float f) {
    unsigned int b = __float_as_uint(f);
    b += 0x7FFFu + ((b >> 16) & 1u);
    return (ushort_t)(b >> 16);
}
__device__ __forceinline__ float bf16_to_f32(ushort_t u) {
    return __uint_as_float(((unsigned int)u) << 16);
}
__device__ __forceinline__ unsigned int pack_bf16(float lo, float hi) {
    return (unsigned int)f32_to_bf16(lo) | ((unsigned int)f32_to_bf16(hi) << 16);
}
// 8 consecutive fp32 -> bf16x8 MFMA fragment (j-order = k-order)
__device__ __forceinline__ bf16x8 pack8w(const float* __restrict__ p) {
    bf16x8 r;
#pragma unroll
    for (int j = 0; j < 8; ++j) r[j] = (short)f32_to_bf16(p[j]);
    return r;
}

// ---------------------------------------------------------------------------
// Prepass: x fp32 -> bf16, XCD-pinned. (R5 verbatim)
// ---------------------------------------------------------------------------
__global__ __launch_bounds__(256) void pm_conv(
    const f32x4* __restrict__ x, uint4* __restrict__ xb)
{
    const int l = xcd_swz(blockIdx.x, NBLK_CONV / 8);
    const size_t i = (size_t)l * 256 + threadIdx.x;
    const f32x4 a = __builtin_nontemporal_load(&x[2 * i]);
    const f32x4 c = __builtin_nontemporal_load(&x[2 * i + 1]);
    uint4 o;
    o.x = pack_bf16(a.x, a.y);
    o.y = pack_bf16(a.z, a.w);
    o.z = pack_bf16(c.x, c.y);
    o.w = pack_bf16(c.z, c.w);
    xb[i] = o;
}

// ---------------------------------------------------------------------------
// Stage 1, MFMA edition. Per block: 32 rows.
//  phase 1: gather+blend 32 rows (8 passes, wave w = row 4p+w, NO barriers),
//           s1 -> bf16 LDS, XOR-swizzled (byte ^= (row&7)<<4) for frag reads.
//  phase 2: stage A = 8x GEMM [M=32 rows, N=32 q, K=32 p] via 16x16x32 MFMA;
//           f written to LDS as fs[row][l=h&7][r=h>>3] (stage-B frag layout).
//  phase 3: stage B = 8x GEMM [M=32, N=32 s, K=32 r] + bias -> bf16 staging.
//  phase 4: coalesced t writeout.
// Replaces ~2048 ds_read_b128/block (32x read amplification, the measured
// ~80% LDS-unit occupancy) with 16 frag reads + 64 MFMA per block.
// ---------------------------------------------------------------------------
__global__ __launch_bounds__(256, 4) void pm_stage1(
    const ushort_t* __restrict__ xb, const float* __restrict__ dist,
    const int* __restrict__ idx, const float* __restrict__ w1,
    const float* __restrict__ w2, const float* __restrict__ bias,
    ushort_t* __restrict__ t)
{
    const int lane = threadIdx.x & 63;
    const int wv   = __builtin_amdgcn_readfirstlane(threadIdx.x >> 6);

    __shared__ __align__(16) unsigned char s1b[RPB_S1 * 512]; // bf16 [32][256]; reused as t-staging
    __shared__ __align__(16) unsigned char fsb[RPB_S1 * 512]; // bf16 [32][8][32] (row, l, r)

    const int lb       = xcd_swz(blockIdx.x, NBLK_S1 / 8);
    const int row_base = lb * RPB_S1;
    const int b        = row_base >> 13;           // batch == XCD id
    const char* xbase  = (const char*)(xb + (size_t)b * NPTS * CH);
    const int laneoff  = lane * 8;                 // 8 B per ushort4

    // ============ phase 1: gather + blend (8 passes, no barriers) ==========
    float dcur[KNB]; int nbs[KNB];
    {
        const int row = row_base + wv;
        const float4 d0 = *(const float4*)(dist + (size_t)row * KNB);
        const float4 d1 = *(const float4*)(dist + (size_t)row * KNB + 4);
        const int4   i0 = *(const int4*)(idx + (size_t)row * KNB);
        const int4   i1 = *(const int4*)(idx + (size_t)row * KNB + 4);
        dcur[0]=d0.x; dcur[1]=d0.y; dcur[2]=d0.z; dcur[3]=d0.w;
        dcur[4]=d1.x; dcur[5]=d1.y; dcur[6]=d1.z; dcur[7]=d1.w;
        nbs[0]=__builtin_amdgcn_readfirstlane(i0.x);
        nbs[1]=__builtin_amdgcn_readfirstlane(i0.y);
        nbs[2]=__builtin_amdgcn_readfirstlane(i0.z);
        nbs[3]=__builtin_amdgcn_readfirstlane(i0.w);
        nbs[4]=__builtin_amdgcn_readfirstlane(i1.x);
        nbs[5]=__builtin_amdgcn_readfirstlane(i1.y);
        nbs[6]=__builtin_amdgcn_readfirstlane(i1.z);
        nbs[7]=__builtin_amdgcn_readfirstlane(i1.w);
    }
    ushort4 c0, g[KNB];
    {
        const int rloc = (row_base + wv) & (NPTS - 1);
        c0 = *(const ushort4*)(xbase + ((size_t)rloc << 9) + laneoff);
#pragma unroll
        for (int k = 0; k < KNB; ++k)
            g[k] = *(const ushort4*)(xbase + ((size_t)(unsigned)nbs[k] << 9) + laneoff);
    }

#pragma unroll
    for (int p = 0; p < 8; ++p) {
        const int rl = p * 4 + wv;                  // local row this wave blends

        float mn = dcur[0];
#pragma unroll
        for (int k = 1; k < KNB; ++k) mn = fminf(mn, dcur[k]);
        float e[KNB]; float sum = 0.f;
#pragma unroll
        for (int k = 0; k < KNB; ++k) { e[k] = __expf(mn - dcur[k]); sum += e[k]; }
        const float inv = 0.05f / sum;

        // prefetch next row's metadata (in flight during the blend)
        float4 dn0, dn1; int4 in0, in1;
        if (p < 7) {
            const int rown = row_base + (p + 1) * 4 + wv;
            dn0 = *(const float4*)(dist + (size_t)rown * KNB);
            dn1 = *(const float4*)(dist + (size_t)rown * KNB + 4);
            in0 = *(const int4*)(idx + (size_t)rown * KNB);
            in1 = *(const int4*)(idx + (size_t)rown * KNB + 4);
        }

        float4 acc;
        acc.x = 0.95f * bf16_to_f32(c0.x);
        acc.y = 0.95f * bf16_to_f32(c0.y);
        acc.z = 0.95f * bf16_to_f32(c0.z);
        acc.w = 0.95f * bf16_to_f32(c0.w);
#pragma unroll
        for (int k = 0; k < KNB; ++k) {
            const float w = e[k] * inv;
            acc.x += w * bf16_to_f32(g[k].x);
            acc.y += w * bf16_to_f32(g[k].y);
            acc.z += w * bf16_to_f32(g[k].z);
            acc.w += w * bf16_to_f32(g[k].w);
        }
        // write s1 row as bf16, XOR-swizzled (16B-slot spread across 8 rows)
        uint2 pv;
        pv.x = pack_bf16(acc.x, acc.y);
        pv.y = pack_bf16(acc.z, acc.w);
        *(uint2*)(s1b + rl * 512 + ((lane * 8) ^ ((rl & 7) << 4))) = pv;

        // rotate meta + issue next row's gathers (fly across next weights calc)
        if (p < 7) {
            dcur[0]=dn0.x; dcur[1]=dn0.y; dcur[2]=dn0.z; dcur[3]=dn0.w;
            dcur[4]=dn1.x; dcur[5]=dn1.y; dcur[6]=dn1.z; dcur[7]=dn1.w;
            nbs[0]=__builtin_amdgcn_readfirstlane(in0.x);
            nbs[1]=__builtin_amdgcn_readfirstlane(in0.y);
            nbs[2]=__builtin_amdgcn_readfirstlane(in0.z);
            nbs[3]=__builtin_amdgcn_readfirstlane(in0.w);
            nbs[4]=__builtin_amdgcn_readfirstlane(in1.x);
            nbs[5]=__builtin_amdgcn_readfirstlane(in1.y);
            nbs[6]=__builtin_amdgcn_readfirstlane(in1.z);
            nbs[7]=__builtin_amdgcn_readfirstlane(in1.w);
            const int rloc = (row_base + (p + 1) * 4 + wv) & (NPTS - 1);
            c0 = *(const ushort4*)(xbase + ((size_t)rloc << 9) + laneoff);
#pragma unroll
            for (int k = 0; k < KNB; ++k)
                g[k] = *(const ushort4*)(xbase + ((size_t)(unsigned)nbs[k] << 9) + laneoff);
        }
    }

    BARRIER_LDS();   // all 32 s1 rows visible

    // ============ phase 2: stage A via MFMA (wave wv: kb = 2wv, 2wv+1) =====
    // f[row][kb*32+q] = sum_p s1[row][kb*32+p] * w1[kb][q][p]
    // A: m=lane&15(+mt*16)=row, k=(lane>>4)*8+j=p ; B: n=lane&15(+nt*16)=q
    // C/D: col=lane&15, row=(lane>>4)*4+reg   [verified m89/m91]
    const int l15 = lane & 15;
    const int kq  = lane >> 4;                      // k-group 0..3
#pragma unroll
    for (int kk = 0; kk < 2; ++kk) {
        const int kb = wv * 2 + kk;
        const int ao = (kb * 64 + kq * 16);
        const bf16x8 a0 = *(const bf16x8*)(s1b + l15 * 512        + (ao ^ ((l15 & 7) << 4)));
        const bf16x8 a1 = *(const bf16x8*)(s1b + (16 + l15) * 512 + (ao ^ (((16 + l15) & 7) << 4)));
        const bf16x8 b0 = pack8w(w1 + (size_t)(kb * 32 + l15) * 32 + kq * 8);
        const bf16x8 b1 = pack8w(w1 + (size_t)(kb * 32 + 16 + l15) * 32 + kq * 8);
        f32x4 d00 = {0.f,0.f,0.f,0.f}, d01 = d00, d10 = d00, d11 = d00;
        d00 = __builtin_amdgcn_mfma_f32_16x16x32_bf16(a0, b0, d00, 0, 0, 0);
        d01 = __builtin_amdgcn_mfma_f32_16x16x32_bf16(a0, b1, d01, 0, 0, 0);
        d10 = __builtin_amdgcn_mfma_f32_16x16x32_bf16(a1, b0, d10, 0, 0, 0);
        d11 = __builtin_amdgcn_mfma_f32_16x16x32_bf16(a1, b1, d11, 0, 0, 0);
        // scatter f -> fs[row][l=q&7][r=kb*4+(q>>3)] bf16 (stage-B frag layout)
#pragma unroll
        for (int nt = 0; nt < 2; ++nt) {
            const int qq = nt * 16 + l15;
            const int fo = (qq & 7) * 64 + (kb * 4 + (qq >> 3)) * 2;
#pragma unroll
            for (int mt = 0; mt < 2; ++mt) {
                const f32x4 dd = (mt == 0) ? (nt == 0 ? d00 : d01)
                                           : (nt == 0 ? d10 : d11);
#pragma unroll
                for (int reg = 0; reg < 4; ++reg) {
                    const int row = mt * 16 + kq * 4 + reg;
                    *(ushort_t*)(fsb + row * 512 + (fo ^ ((row & 7) << 4))) =
                        f32_to_bf16(dd[reg]);
                }
            }
        }
    }

    BARRIER_LDS();   // fs complete

    // ============ phase 3: stage B via MFMA (wave wv: l2 = 2wv, 2wv+1) =====
    // t[row][s*8+l2] = bias + sum_r fs[row][l2][r] * w2[l2][s][r]
#pragma unroll
    for (int kk = 0; kk < 2; ++kk) {
        const int l2 = wv * 2 + kk;
        const int ao = (l2 * 64 + kq * 16);
        const bf16x8 a0 = *(const bf16x8*)(fsb + l15 * 512        + (ao ^ ((l15 & 7) << 4)));
        const bf16x8 a1 = *(const bf16x8*)(fsb + (16 + l15) * 512 + (ao ^ (((16 + l15) & 7) << 4)));
        const bf16x8 b0 = pack8w(w2 + (size_t)(l2 * 32 + l15) * 32 + kq * 8);
        const bf16x8 b1 = pack8w(w2 + (size_t)(l2 * 32 + 16 + l15) * 32 + kq * 8);
        f32x4 d00 = {0.f,0.f,0.f,0.f}, d01 = d00, d10 = d00, d11 = d00;
        d00 = __builtin_amdgcn_mfma_f32_16x16x32_bf16(a0, b0, d00, 0, 0, 0);
        d01 = __builtin_amdgcn_mfma_f32_16x16x32_bf16(a0, b1, d01, 0, 0, 0);
        d10 = __builtin_amdgcn_mfma_f32_16x16x32_bf16(a1, b0, d10, 0, 0, 0);
        d11 = __builtin_amdgcn_mfma_f32_16x16x32_bf16(a1, b1, d11, 0, 0, 0);
        // scatter t-values (+bias) into s1b as bf16 staging (plain layout)
#pragma unroll
        for (int nt = 0; nt < 2; ++nt) {
            const int cD = (nt * 16 + l15) * 8 + l2;
            const float bv = bias[cD];
#pragma unroll
            for (int mt = 0; mt < 2; ++mt) {
                const f32x4 dd = (mt == 0) ? (nt == 0 ? d00 : d01)
                                           : (nt == 0 ? d10 : d11);
#pragma unroll
                for (int reg = 0; reg < 4; ++reg) {
                    const int row = mt * 16 + kq * 4 + reg;
                    *(ushort_t*)(s1b + row * 512 + cD * 2) =
                        f32_to_bf16(dd[reg] + bv);
                }
            }
        }
    }

    BARRIER_LDS();   // t staging complete

    // ============ phase 4: coalesced t writeout (wave wv: rows 8wv..+8) ====
    // normal stores: t write-allocates in this XCD's L2 for stage2 (R5 lesson)
#pragma unroll
    for (int r = 0; r < 8; ++r) {
        const int row = wv * 8 + r;
        const uint2 v = *(const uint2*)(s1b + row * 512 + lane * 8);
        *(uint2*)((char*)t + ((size_t)(row_base + row) << 9) + lane * 8) = v;
    }
}

// ---------------------------------------------------------------------------
// Stage 2: out = 0.95*t + 0.05*sum_k w_k*t[b,idx_k] + rf  (R5 verbatim)
// ---------------------------------------------------------------------------
__global__ __launch_bounds__(256, 4) void pm_stage2(
    const ushort_t* __restrict__ t, const float* __restrict__ dist,
    const int* __restrict__ idx, const float* __restrict__ rf,
    float* __restrict__ out)
{
    const int w     = __builtin_amdgcn_readfirstlane(threadIdx.x >> 6);
    const int lane  = threadIdx.x & 63;
    const int lb    = xcd_swz(blockIdx.x, NBLK_S2 / 8);
    const int wrow0 = lb * 16 + w * 4;
    const int b     = wrow0 >> 13;
    const char* tbase = (const char*)(t + (size_t)b * NPTS * CH);
    const int laneoff = lane * 8;

    int   nbs[4][KNB];
    float d [4][KNB];
#pragma unroll
    for (int r = 0; r < 4; ++r) {
        const int row = wrow0 + r;
        const float4 d0 = *(const float4*)(dist + (size_t)row * KNB);
        const float4 d1 = *(const float4*)(dist + (size_t)row * KNB + 4);
        const int4   i0 = *(const int4*)(idx + (size_t)row * KNB);
        const int4   i1 = *(const int4*)(idx + (size_t)row * KNB + 4);
        d[r][0]=d0.x; d[r][1]=d0.y; d[r][2]=d0.z; d[r][3]=d0.w;
        d[r][4]=d1.x; d[r][5]=d1.y; d[r][6]=d1.z; d[r][7]=d1.w;
        nbs[r][0]=__builtin_amdgcn_readfirstlane(i0.x);
        nbs[r][1]=__builtin_amdgcn_readfirstlane(i0.y);
        nbs[r][2]=__builtin_amdgcn_readfirstlane(i0.z);
        nbs[r][3]=__builtin_amdgcn_readfirstlane(i0.w);
        nbs[r][4]=__builtin_amdgcn_readfirstlane(i1.x);
        nbs[r][5]=__builtin_amdgcn_readfirstlane(i1.y);
        nbs[r][6]=__builtin_amdgcn_readfirstlane(i1.z);
        nbs[r][7]=__builtin_amdgcn_readfirstlane(i1.w);
    }

    ushort4 c0[4], g[4][KNB];
    f32x4   rv[4];
#pragma unroll
    for (int r = 0; r < 4; ++r) {
        const int rloc = (wrow0 + r) & (NPTS - 1);
        c0[r] = *(const ushort4*)(tbase + ((size_t)rloc << 9) + laneoff);
        rv[r] = __builtin_nontemporal_load(
                    &((const f32x4*)rf)[(size_t)(wrow0 + r) * 64 + lane]);
#pragma unroll
        for (int k = 0; k < KNB; ++k)
            g[r][k] = *(const ushort4*)(tbase + ((size_t)(unsigned)nbs[r][k] << 9) + laneoff);
    }

#pragma unroll
    for (int r = 0; r < 4; ++r) {
        float mn = d[r][0];
#pragma unroll
        for (int k = 1; k < KNB; ++k) mn = fminf(mn, d[r][k]);
        float e[KNB]; float sum = 0.f;
#pragma unroll
        for (int k = 0; k < KNB; ++k) { e[k] = __expf(mn - d[r][k]); sum += e[k]; }
        const float inv = 0.05f / sum;

        f32x4 acc;
        acc.x = 0.95f * bf16_to_f32(c0[r].x) + rv[r].x;
        acc.y = 0.95f * bf16_to_f32(c0[r].y) + rv[r].y;
        acc.z = 0.95f * bf16_to_f32(c0[r].z) + rv[r].z;
        acc.w = 0.95f * bf16_to_f32(c0[r].w) + rv[r].w;
#pragma unroll
        for (int k = 0; k < KNB; ++k) {
            const float wk = e[k] * inv;
            acc.x += wk * bf16_to_f32(g[r][k].x);
            acc.y += wk * bf16_to_f32(g[r][k].y);
            acc.z += wk * bf16_to_f32(g[r][k].z);
            acc.w += wk * bf16_to_f32(g[r][k].w);
        }
        __builtin_nontemporal_store(
            acc, &((f32x4*)out)[(size_t)(wrow0 + r) * 64 + lane]);
    }
}

extern "C" void kernel_launch(void* const* d_in, const int* in_sizes, int n_in,
                              void* d_out, int out_size, void* d_ws, size_t ws_size,
                              hipStream_t stream) {
    const float* x    = (const float*)d_in[0];
    const float* dist = (const float*)d_in[1];
    const int*   idx  = (const int*)d_in[2];
    const float* rf   = (const float*)d_in[3];
    const float* w1   = (const float*)d_in[4];
    const float* w2   = (const float*)d_in[5];
    const float* bias = (const float*)d_in[6];
    float* out = (float*)d_out;

    ushort_t* t  = (ushort_t*)d_ws;                                   // 32 MiB bf16 t
    ushort_t* xb = (ushort_t*)((char*)d_ws + (size_t)NROWS * CH * 2); // 32 MiB bf16 x

    pm_conv  <<<NBLK_CONV, 256, 0, stream>>>((const f32x4*)x, (uint4*)xb);
    pm_stage1<<<NBLK_S1,   256, 0, stream>>>(xb, dist, idx, w1, w2, bias, t);
    pm_stage2<<<NBLK_S2,   256, 0, stream>>>(t, dist, idx, rf, out);
}

// Round 10
// 236.619 us; speedup vs baseline: 1.1863x; 1.0083x over previous
//
#include <hip/hip_runtime.h>

// Problem constants (B=8, N=8192, C=256, K=8, nblocks=8, blk=32)
#define NPTS 8192
#define CH   256
#define KNB  8
#define NROWS 65536        // B*N
#define RPB_S1 32
#define NBLK_CONV 8192     // NROWS*CH/(256*8)
#define NBLK_S1   (NROWS / RPB_S1)   // 2048
#define NBLK_S2   (NROWS / 16)       // 4096

// LDS strides chosen for bank spread (non-128B-multiple rows, non-64B l-stride)
#define S1_STRIDE 544      // s1 blend buffer / t staging: 32 x 544 = 17,408 B
#define FS_STRIDE 656      // f buffer row stride:          32 x 656 = 20,992 B
#define FS_L      80       // f l-stride (8 l x 80 B; r*2 <= 64 < 80)

typedef unsigned short ushort_t;
typedef float  f32x4  __attribute__((ext_vector_type(4)));   // nontemporal + MFMA C/D
typedef short  bf16x8 __attribute__((ext_vector_type(8)));   // MFMA A/B frag (8 bf16)

// Raw barrier: LDS ordering only; global loads stay in flight across it.
#define BARRIER_LDS() do { \
    asm volatile("s_waitcnt lgkmcnt(0)" ::: "memory"); \
    __builtin_amdgcn_s_barrier(); \
} while (0)

// XCD-aware swizzle: 8 batches == 8 XCDs; XCD i owns batch i (4 MB slice in L2).
__device__ __forceinline__ int xcd_swz(int h, int cpx) {
    return (h & 7) * cpx + (h >> 3);     // bijective: grid % 8 == 0 everywhere
}

__device__ __forceinline__ ushort_t f32_to_bf16(float f) {
    unsigned int b = __float_as_uint(f);
    b += 0x7FFFu + ((b >> 16) & 1u);
    return (ushort_t)(b >> 16);
}
__device__ __forceinline__ float bf16_to_f32(ushort_t u) {
    return __uint_as_float(((unsigned int)u) << 16);
}
__device__ __forceinline__ unsigned int pack_bf16(float lo, float hi) {
    return (unsigned int)f32_to_bf16(lo) | ((unsigned int)f32_to_bf16(hi) << 16);
}
__device__ __forceinline__ bf16x8 pack8w(const float* __restrict__ p) {
    bf16x8 r;
#pragma unroll
    for (int j = 0; j < 8; ++j) r[j] = (short)f32_to_bf16(p[j]);
    return r;
}

// Swizzled LDS addressing: XOR row bits into 16B-slot bits (bits 4-6).
// Applied consistently on writes AND reads -> involution, layout-consistent.
__device__ __forceinline__ unsigned char* s1addr(unsigned char* base, int row, int byte_off) {
    return base + row * S1_STRIDE + (byte_off ^ ((row & 7) << 4));
}
__device__ __forceinline__ unsigned char* fsaddr(unsigned char* base, int row, int byte_off) {
    return base + row * FS_STRIDE + (byte_off ^ ((row & 7) << 4));
}

// ---------------------------------------------------------------------------
// Prepass: x fp32 -> bf16, XCD-pinned. (R9 verbatim)
// ---------------------------------------------------------------------------
__global__ __launch_bounds__(256) void pm_conv(
    const f32x4* __restrict__ x, uint4* __restrict__ xb)
{
    const int l = xcd_swz(blockIdx.x, NBLK_CONV / 8);
    const size_t i = (size_t)l * 256 + threadIdx.x;
    const f32x4 a = __builtin_nontemporal_load(&x[2 * i]);
    const f32x4 c = __builtin_nontemporal_load(&x[2 * i + 1]);
    uint4 o;
    o.x = pack_bf16(a.x, a.y);
    o.y = pack_bf16(a.z, a.w);
    o.z = pack_bf16(c.x, c.y);
    o.w = pack_bf16(c.z, c.w);
    xb[i] = o;
}

// ---------------------------------------------------------------------------
// Stage 1, MFMA edition v2.
//  phase 1: blend 32 rows, TWO-DEEP gather pipeline (sets A/B rotate; the
//           consumed set always has ~2 blend-durations of latency cover).
//  phase 2: stage A = GEMMs via 16x16x32 MFMA; f scattered b16 into fsb
//           (l-stride 80 / row-stride 656: 16 distinct banks per store inst
//           vs the banks {0,16} 32-way collision measured in R9: 4.7M conflicts).
//  phase 3: stage B MFMA; wave wv owns l2 = {2wv, 2wv+1} -> channels c,c+1
//           are IN-LANE -> pack_bf16 pairs -> 16 b32 stores (was 32 b16).
//  phase 4: coalesced t writeout (normal stores: t L2-resident for stage2).
// ---------------------------------------------------------------------------
__global__ __launch_bounds__(256, 4) void pm_stage1(
    const ushort_t* __restrict__ xb, const float* __restrict__ dist,
    const int* __restrict__ idx, const float* __restrict__ w1,
    const float* __restrict__ w2, const float* __restrict__ bias,
    ushort_t* __restrict__ t)
{
    const int lane = threadIdx.x & 63;
    const int wv   = __builtin_amdgcn_readfirstlane(threadIdx.x >> 6);

    __shared__ __align__(16) unsigned char s1b[RPB_S1 * S1_STRIDE];
    __shared__ __align__(16) unsigned char fsb[RPB_S1 * FS_STRIDE];

    const int lb       = xcd_swz(blockIdx.x, NBLK_S1 / 8);
    const int row_base = lb * RPB_S1;
    const int b        = row_base >> 13;           // batch == XCD id
    const char* xbase  = (const char*)(xb + (size_t)b * NPTS * CH);
    const int laneoff  = lane * 8;                 // 8 B per ushort4

#define LOAD_META(dd, nn, row) do {                                        \
    const float4 m0_ = *(const float4*)(dist + (size_t)(row) * KNB);       \
    const float4 m1_ = *(const float4*)(dist + (size_t)(row) * KNB + 4);   \
    const int4   j0_ = *(const int4*)(idx + (size_t)(row) * KNB);          \
    const int4   j1_ = *(const int4*)(idx + (size_t)(row) * KNB + 4);      \
    dd[0]=m0_.x; dd[1]=m0_.y; dd[2]=m0_.z; dd[3]=m0_.w;                    \
    dd[4]=m1_.x; dd[5]=m1_.y; dd[6]=m1_.z; dd[7]=m1_.w;                    \
    nn[0]=__builtin_amdgcn_readfirstlane(j0_.x);                           \
    nn[1]=__builtin_amdgcn_readfirstlane(j0_.y);                           \
    nn[2]=__builtin_amdgcn_readfirstlane(j0_.z);                           \
    nn[3]=__builtin_amdgcn_readfirstlane(j0_.w);                           \
    nn[4]=__builtin_amdgcn_readfirstlane(j1_.x);                           \
    nn[5]=__builtin_amdgcn_readfirstlane(j1_.y);                           \
    nn[6]=__builtin_amdgcn_readfirstlane(j1_.z);                           \
    nn[7]=__builtin_amdgcn_readfirstlane(j1_.w);                           \
} while (0)

#define ISSUE_G(cc, gg, nn, row) do {                                      \
    const int rloc_ = (row) & (NPTS - 1);                                  \
    cc = *(const ushort4*)(xbase + ((size_t)rloc_ << 9) + laneoff);        \
    _Pragma("unroll")                                                      \
    for (int k_ = 0; k_ < KNB; ++k_)                                       \
        gg[k_] = *(const ushort4*)(xbase + ((size_t)(unsigned)nn[k_] << 9) + laneoff); \
} while (0)

#define BLEND_W(cc, gg, dd, rl_) do {                                      \
    float mn_ = dd[0];                                                     \
    _Pragma("unroll")                                                      \
    for (int k_ = 1; k_ < KNB; ++k_) mn_ = fminf(mn_, dd[k_]);             \
    float e_[KNB]; float sum_ = 0.f;                                       \
    _Pragma("unroll")                                                      \
    for (int k_ = 0; k_ < KNB; ++k_) { e_[k_] = __expf(mn_ - dd[k_]); sum_ += e_[k_]; } \
    const float inv_ = 0.05f / sum_;                                       \
    float ax_ = 0.95f * bf16_to_f32(cc.x);                                 \
    float ay_ = 0.95f * bf16_to_f32(cc.y);                                 \
    float az_ = 0.95f * bf16_to_f32(cc.z);                                 \
    float aw_ = 0.95f * bf16_to_f32(cc.w);                                 \
    _Pragma("unroll")                                                      \
    for (int k_ = 0; k_ < KNB; ++k_) {                                     \
        const float w_ = e_[k_] * inv_;                                    \
        ax_ += w_ * bf16_to_f32(gg[k_].x);                                 \
        ay_ += w_ * bf16_to_f32(gg[k_].y);                                 \
        az_ += w_ * bf16_to_f32(gg[k_].z);                                 \
        aw_ += w_ * bf16_to_f32(gg[k_].w);                                 \
    }                                                                      \
    uint2 pv_;                                                             \
    pv_.x = pack_bf16(ax_, ay_);                                           \
    pv_.y = pack_bf16(az_, aw_);                                           \
    *(uint2*)s1addr(s1b, rl_, lane * 8) = pv_;                             \
} while (0)

    // ============ phase 1: blend, two-deep gather pipeline =================
    float dA[KNB], dB[KNB];
    int   nA[KNB], nB[KNB];
    ushort4 cA, gA[KNB], cB, gB[KNB];

    LOAD_META(dA, nA, row_base + wv);
    LOAD_META(dB, nB, row_base + 4 + wv);
    ISSUE_G(cA, gA, nA, row_base + wv);
    ISSUE_G(cB, gB, nB, row_base + 4 + wv);

#pragma unroll
    for (int p = 0; p < 8; ++p) {
        const int rl   = p * 4 + wv;
        const int rown = row_base + (p + 2) * 4 + wv;

        // raw meta prefetch for p+2 (in flight during the blend)
        float4 dn0, dn1; int4 in0, in1;
        if (p < 6) {
            dn0 = *(const float4*)(dist + (size_t)rown * KNB);
            dn1 = *(const float4*)(dist + (size_t)rown * KNB + 4);
            in0 = *(const int4*)(idx + (size_t)rown * KNB);
            in1 = *(const int4*)(idx + (size_t)rown * KNB + 4);
        }

        if ((p & 1) == 0) {
            BLEND_W(cA, gA, dA, rl);
            if (p < 6) {
                dA[0]=dn0.x; dA[1]=dn0.y; dA[2]=dn0.z; dA[3]=dn0.w;
                dA[4]=dn1.x; dA[5]=dn1.y; dA[6]=dn1.z; dA[7]=dn1.w;
                nA[0]=__builtin_amdgcn_readfirstlane(in0.x);
                nA[1]=__builtin_amdgcn_readfirstlane(in0.y);
                nA[2]=__builtin_amdgcn_readfirstlane(in0.z);
                nA[3]=__builtin_amdgcn_readfirstlane(in0.w);
                nA[4]=__builtin_amdgcn_readfirstlane(in1.x);
                nA[5]=__builtin_amdgcn_readfirstlane(in1.y);
                nA[6]=__builtin_amdgcn_readfirstlane(in1.z);
                nA[7]=__builtin_amdgcn_readfirstlane(in1.w);
                ISSUE_G(cA, gA, nA, rown);
            }
        } else {
            BLEND_W(cB, gB, dB, rl);
            if (p < 6) {
                dB[0]=dn0.x; dB[1]=dn0.y; dB[2]=dn0.z; dB[3]=dn0.w;
                dB[4]=dn1.x; dB[5]=dn1.y; dB[6]=dn1.z; dB[7]=dn1.w;
                nB[0]=__builtin_amdgcn_readfirstlane(in0.x);
                nB[1]=__builtin_amdgcn_readfirstlane(in0.y);
                nB[2]=__builtin_amdgcn_readfirstlane(in0.z);
                nB[3]=__builtin_amdgcn_readfirstlane(in0.w);
                nB[4]=__builtin_amdgcn_readfirstlane(in1.x);
                nB[5]=__builtin_amdgcn_readfirstlane(in1.y);
                nB[6]=__builtin_amdgcn_readfirstlane(in1.z);
                nB[7]=__builtin_amdgcn_readfirstlane(in1.w);
                ISSUE_G(cB, gB, nB, rown);
            }
        }
    }
#undef LOAD_META
#undef ISSUE_G
#undef BLEND_W

    BARRIER_LDS();   // all 32 s1 rows visible

    // ============ phase 2: stage A via MFMA (wave wv: kb = 2wv, 2wv+1) =====
    // f[row][kb*32+q] = sum_p s1[row][kb*32+p] * w1[kb][q][p]
    // A: m=row=lane&15(+16mt), k=p=(lane>>4)*8+j ; B: n=q ; C/D col=lane&15,
    // row=(lane>>4)*4+reg  [verified m89/m91]
    const int l15 = lane & 15;
    const int kq  = lane >> 4;
#pragma unroll
    for (int kk = 0; kk < 2; ++kk) {
        const int kb = wv * 2 + kk;
        const int ao = kb * 64 + kq * 16;
        const bf16x8 a0 = *(const bf16x8*)s1addr(s1b, l15, ao);
        const bf16x8 a1 = *(const bf16x8*)s1addr(s1b, 16 + l15, ao);
        const bf16x8 b0 = pack8w(w1 + (size_t)(kb * 32 + l15) * 32 + kq * 8);
        const bf16x8 b1 = pack8w(w1 + (size_t)(kb * 32 + 16 + l15) * 32 + kq * 8);
        f32x4 d00 = {0.f,0.f,0.f,0.f}, d01 = d00, d10 = d00, d11 = d00;
        d00 = __builtin_amdgcn_mfma_f32_16x16x32_bf16(a0, b0, d00, 0, 0, 0);
        d01 = __builtin_amdgcn_mfma_f32_16x16x32_bf16(a0, b1, d01, 0, 0, 0);
        d10 = __builtin_amdgcn_mfma_f32_16x16x32_bf16(a1, b0, d10, 0, 0, 0);
        d11 = __builtin_amdgcn_mfma_f32_16x16x32_bf16(a1, b1, d11, 0, 0, 0);
        // scatter f -> fsb[row][l=h&7][r=h>>3], h = kb*32+q (b16, bank-spread)
#pragma unroll
        for (int nt = 0; nt < 2; ++nt) {
            const int qq = nt * 16 + l15;
            const int fo = (qq & 7) * FS_L + (kb * 4 + (qq >> 3)) * 2;
#pragma unroll
            for (int mt = 0; mt < 2; ++mt) {
                const f32x4 dd = (mt == 0) ? (nt == 0 ? d00 : d01)
                                           : (nt == 0 ? d10 : d11);
#pragma unroll
                for (int reg = 0; reg < 4; ++reg) {
                    const int row = mt * 16 + kq * 4 + reg;
                    *(ushort_t*)fsaddr(fsb, row, fo) = f32_to_bf16(dd[reg]);
                }
            }
        }
    }

    BARRIER_LDS();   // fs complete

    // ============ phase 3: stage B via MFMA, l2-pair packed output =========
    // t[row][q*8+l2] = bias + sum_r fs[row][l2][r] * w2[l2][s=q][r]
    // wave wv owns l2 = 2wv (kk0) and 2wv+1 (kk1): channels c,c+1 in-lane.
    {
        const int l20 = wv * 2;
        const bf16x8 fa00 = *(const bf16x8*)fsaddr(fsb, l15,      l20 * FS_L + kq * 16);
        const bf16x8 fa01 = *(const bf16x8*)fsaddr(fsb, 16 + l15, l20 * FS_L + kq * 16);
        const bf16x8 fa10 = *(const bf16x8*)fsaddr(fsb, l15,      (l20 + 1) * FS_L + kq * 16);
        const bf16x8 fa11 = *(const bf16x8*)fsaddr(fsb, 16 + l15, (l20 + 1) * FS_L + kq * 16);
        const bf16x8 wb00 = pack8w(w2 + (size_t)(l20 * 32 + l15) * 32 + kq * 8);
        const bf16x8 wb01 = pack8w(w2 + (size_t)(l20 * 32 + 16 + l15) * 32 + kq * 8);
        const bf16x8 wb10 = pack8w(w2 + (size_t)((l20 + 1) * 32 + l15) * 32 + kq * 8);
        const bf16x8 wb11 = pack8w(w2 + (size_t)((l20 + 1) * 32 + 16 + l15) * 32 + kq * 8);
        f32x4 z = {0.f, 0.f, 0.f, 0.f};
        f32x4 D0m0n0 = __builtin_amdgcn_mfma_f32_16x16x32_bf16(fa00, wb00, z, 0, 0, 0);
        f32x4 D0m0n1 = __builtin_amdgcn_mfma_f32_16x16x32_bf16(fa00, wb01, z, 0, 0, 0);
        f32x4 D0m1n0 = __builtin_amdgcn_mfma_f32_16x16x32_bf16(fa01, wb00, z, 0, 0, 0);
        f32x4 D0m1n1 = __builtin_amdgcn_mfma_f32_16x16x32_bf16(fa01, wb01, z, 0, 0, 0);
        f32x4 D1m0n0 = __builtin_amdgcn_mfma_f32_16x16x32_bf16(fa10, wb10, z, 0, 0, 0);
        f32x4 D1m0n1 = __builtin_amdgcn_mfma_f32_16x16x32_bf16(fa10, wb11, z, 0, 0, 0);
        f32x4 D1m1n0 = __builtin_amdgcn_mfma_f32_16x16x32_bf16(fa11, wb10, z, 0, 0, 0);
        f32x4 D1m1n1 = __builtin_amdgcn_mfma_f32_16x16x32_bf16(fa11, wb11, z, 0, 0, 0);

#pragma unroll
        for (int nt = 0; nt < 2; ++nt) {
            const int q   = nt * 16 + l15;
            const float bv0 = bias[q * 8 + l20];
            const float bv1 = bias[q * 8 + l20 + 1];
#pragma unroll
            for (int mt = 0; mt < 2; ++mt) {
                const f32x4 e0 = (mt == 0) ? (nt == 0 ? D0m0n0 : D0m0n1)
                                           : (nt == 0 ? D0m1n0 : D0m1n1);
                const f32x4 e1 = (mt == 0) ? (nt == 0 ? D1m0n0 : D1m0n1)
                                           : (nt == 0 ? D1m1n0 : D1m1n1);
#pragma unroll
                for (int reg = 0; reg < 4; ++reg) {
                    const int row = mt * 16 + kq * 4 + reg;
                    *(unsigned int*)s1addr(s1b, row, q * 16 + wv * 4) =
                        pack_bf16(e0[reg] + bv0, e1[reg] + bv1);
                }
            }
        }
    }

    BARRIER_LDS();   // t staging complete

    // ============ phase 4: coalesced t writeout (wave wv: rows 8wv..+8) ====
#pragma unroll
    for (int r = 0; r < 8; ++r) {
        const int row = wv * 8 + r;
        const uint2 v = *(const uint2*)s1addr(s1b, row, lane * 8);
        *(uint2*)((char*)t + ((size_t)(row_base + row) << 9) + lane * 8) = v;
    }
}

// ---------------------------------------------------------------------------
// Stage 2: out = 0.95*t + 0.05*sum_k w_k*t[b,idx_k] + rf  (R9 verbatim)
// ---------------------------------------------------------------------------
__global__ __launch_bounds__(256, 4) void pm_stage2(
    const ushort_t* __restrict__ t, const float* __restrict__ dist,
    const int* __restrict__ idx, const float* __restrict__ rf,
    float* __restrict__ out)
{
    const int w     = __builtin_amdgcn_readfirstlane(threadIdx.x >> 6);
    const int lane  = threadIdx.x & 63;
    const int lb    = xcd_swz(blockIdx.x, NBLK_S2 / 8);
    const int wrow0 = lb * 16 + w * 4;
    const int b     = wrow0 >> 13;
    const char* tbase = (const char*)(t + (size_t)b * NPTS * CH);
    const int laneoff = lane * 8;

    int   nbs[4][KNB];
    float d [4][KNB];
#pragma unroll
    for (int r = 0; r < 4; ++r) {
        const int row = wrow0 + r;
        const float4 d0 = *(const float4*)(dist + (size_t)row * KNB);
        const float4 d1 = *(const float4*)(dist + (size_t)row * KNB + 4);
        const int4   i0 = *(const int4*)(idx + (size_t)row * KNB);
        const int4   i1 = *(const int4*)(idx + (size_t)row * KNB + 4);
        d[r][0]=d0.x; d[r][1]=d0.y; d[r][2]=d0.z; d[r][3]=d0.w;
        d[r][4]=d1.x; d[r][5]=d1.y; d[r][6]=d1.z; d[r][7]=d1.w;
        nbs[r][0]=__builtin_amdgcn_readfirstlane(i0.x);
        nbs[r][1]=__builtin_amdgcn_readfirstlane(i0.y);
        nbs[r][2]=__builtin_amdgcn_readfirstlane(i0.z);
        nbs[r][3]=__builtin_amdgcn_readfirstlane(i0.w);
        nbs[r][4]=__builtin_amdgcn_readfirstlane(i1.x);
        nbs[r][5]=__builtin_amdgcn_readfirstlane(i1.y);
        nbs[r][6]=__builtin_amdgcn_readfirstlane(i1.z);
        nbs[r][7]=__builtin_amdgcn_readfirstlane(i1.w);
    }

    ushort4 c0[4], g[4][KNB];
    f32x4   rv[4];
#pragma unroll
    for (int r = 0; r < 4; ++r) {
        const int rloc = (wrow0 + r) & (NPTS - 1);
        c0[r] = *(const ushort4*)(tbase + ((size_t)rloc << 9) + laneoff);
        rv[r] = __builtin_nontemporal_load(
                    &((const f32x4*)rf)[(size_t)(wrow0 + r) * 64 + lane]);
#pragma unroll
        for (int k = 0; k < KNB; ++k)
            g[r][k] = *(const ushort4*)(tbase + ((size_t)(unsigned)nbs[r][k] << 9) + laneoff);
    }

#pragma unroll
    for (int r = 0; r < 4; ++r) {
        float mn = d[r][0];
#pragma unroll
        for (int k = 1; k < KNB; ++k) mn = fminf(mn, d[r][k]);
        float e[KNB]; float sum = 0.f;
#pragma unroll
        for (int k = 0; k < KNB; ++k) { e[k] = __expf(mn - d[r][k]); sum += e[k]; }
        const float inv = 0.05f / sum;

        f32x4 acc;
        acc.x = 0.95f * bf16_to_f32(c0[r].x) + rv[r].x;
        acc.y = 0.95f * bf16_to_f32(c0[r].y) + rv[r].y;
        acc.z = 0.95f * bf16_to_f32(c0[r].z) + rv[r].z;
        acc.w = 0.95f * bf16_to_f32(c0[r].w) + rv[r].w;
#pragma unroll
        for (int k = 0; k < KNB; ++k) {
            const float wk = e[k] * inv;
            acc.x += wk * bf16_to_f32(g[r][k].x);
            acc.y += wk * bf16_to_f32(g[r][k].y);
            acc.z += wk * bf16_to_f32(g[r][k].z);
            acc.w += wk * bf16_to_f32(g[r][k].w);
        }
        __builtin_nontemporal_store(
            acc, &((f32x4*)out)[(size_t)(wrow0 + r) * 64 + lane]);
    }
}

extern "C" void kernel_launch(void* const* d_in, const int* in_sizes, int n_in,
                              void* d_out, int out_size, void* d_ws, size_t ws_size,
                              hipStream_t stream) {
    const float* x    = (const float*)d_in[0];
    const float* dist = (const float*)d_in[1];
    const int*   idx  = (const int*)d_in[2];
    const float* rf   = (const float*)d_in[3];
    const float* w1   = (const float*)d_in[4];
    const float* w2   = (const float*)d_in[5];
    const float* bias = (const float*)d_in[6];
    float* out = (float*)d_out;

    ushort_t* t  = (ushort_t*)d_ws;                                   // 32 MiB bf16 t
    ushort_t* xb = (ushort_t*)((char*)d_ws + (size_t)NROWS * CH * 2); // 32 MiB bf16 x

    pm_conv  <<<NBLK_CONV, 256, 0, stream>>>((const f32x4*)x, (uint4*)xb);
    pm_stage1<<<NBLK_S1,   256, 0, stream>>>(xb, dist, idx, w1, w2, bias, t);
    pm_stage2<<<NBLK_S2,   256, 0, stream>>>(t, dist, idx, rf, out);
}